// Round 5
// baseline (263.793 us; speedup 1.0000x reference)
//
#include <hip/hip_runtime.h>
#include <stdint.h>

typedef unsigned short u16;
typedef __bf16 bf16x8 __attribute__((ext_vector_type(8)));
typedef u16 u16x8 __attribute__((ext_vector_type(8)));
typedef float f32x4 __attribute__((ext_vector_type(4)));

#define MFMA16(a,b,c) __builtin_amdgcn_mfma_f32_16x16x32_bf16((a),(b),(c),0,0,0)
#define GLOAD16(gp, lp) __builtin_amdgcn_global_load_lds( \
    (const __attribute__((address_space(1))) void*)(gp), \
    (__attribute__((address_space(3))) void*)(lp), 16, 0, 0)

__device__ __forceinline__ u16 f2bf(float f) {
  union { float f; uint32_t u; } v; v.f = f;
  return (u16)((v.u + 0x7FFFu + ((v.u >> 16) & 1u)) >> 16);
}
__device__ __forceinline__ float bits2f(uint32_t u) {
  union { uint32_t u; float f; } v; v.u = u; return v.f;
}
__device__ __forceinline__ uint32_t cvtpk(float lo, float hi) {
  uint32_t r;
  asm("v_cvt_pk_bf16_f32 %0, %1, %2" : "=v"(r) : "v"(lo), "v"(hi));
  return r;
}
__device__ __forceinline__ int4 pack8(const u16* v) {
  int4 r;
  r.x = (int)((uint32_t)v[0] | ((uint32_t)v[1] << 16));
  r.y = (int)((uint32_t)v[2] | ((uint32_t)v[3] << 16));
  r.z = (int)((uint32_t)v[4] | ((uint32_t)v[5] << 16));
  r.w = (int)((uint32_t)v[6] | ((uint32_t)v[7] << 16));
  return r;
}

// ---------------- fp32 -> bf16 convert ----------------
__global__ void k_cvt(const float* __restrict__ in, u16* __restrict__ out, int n4) {
  int i = blockIdx.x * 256 + threadIdx.x;
  int stride = gridDim.x * 256;
  for (; i < n4; i += stride) {
    float4 v = reinterpret_cast<const float4*>(in)[i];
    ushort4 o;
    o.x = f2bf(v.x); o.y = f2bf(v.y); o.z = f2bf(v.z); o.w = f2bf(v.w);
    reinterpret_cast<ushort4*>(out)[i] = o;
  }
}

// ------------- fp32 (R x C) -> bf16 transposed (C x R) -------------
__global__ void k_transpose(const float* __restrict__ in, u16* __restrict__ out, int R, int C) {
  __shared__ float t[32][33];
  int tx = threadIdx.x & 31, ty = threadIdx.x >> 5;
  int c0 = blockIdx.x * 32, r0 = blockIdx.y * 32;
  #pragma unroll
  for (int i = 0; i < 4; i++)
    t[ty + i*8][tx] = in[(size_t)(r0 + ty + i*8) * C + (c0 + tx)];
  __syncthreads();
  #pragma unroll
  for (int i = 0; i < 4; i++)
    out[(size_t)(c0 + ty + i*8) * R + (r0 + tx)] = f2bf(t[tx][ty + i*8]);
}

// =========================================================================
// K1: 256x256 BK=32 pipelined QKV GEMM. 512 thr = 8 waves (2M x 4N).
// 4 K-tile LDS slots (A,B each 16KB/slot -> 128KB). Counted vmcnt(6) schedule.
// LDS layout = R2-proven conflict-free: linear 64B rows, element (row, kslot)
// stored at slot kslot^((row>>1)&3); frag read rsel = g^((c4>>1)&3).
// =========================================================================
__global__ __launch_bounds__(512, 2) void k_qkv256(
    const u16* __restrict__ A, const u16* __restrict__ BT, const float* __restrict__ bias,
    u16* __restrict__ qo, u16* __restrict__ ko, u16* __restrict__ vo)
{
  __shared__ u16 SMEM[65536];   // A slots [0,32768), B slots [32768,65536)

  int bid0 = blockIdx.x;
  // bijective XCD swizzle for 882 = 8*110 + 2
  int xcd = bid0 & 7, idx = bid0 >> 3;
  int base = (xcd < 2) ? xcd * 111 : 2 * 111 + (xcd - 2) * 110;
  int wgid = base + idx;
  int mt = wgid / 9, nt = wgid - (wgid / 9) * 9;

  int tid = threadIdx.x, lane = tid & 63, w = tid >> 6;
  int g = lane >> 4, c4 = lane & 15;
  int wr = w >> 2, wc = w & 3;

  // staging decode (R2 pattern): chunk cid covers 16 rows; this thread loads
  // row cid*16 + srow, source k-slot pslot; HW writes LDS at chunkbase+lane*16.
  int srow = lane >> 2;
  int pslot = (lane & 3) ^ ((lane >> 3) & 3);
  int cidA = w * 2;

  const u16* pA1 = A + (size_t)(mt * 256 + cidA * 16 + srow) * 768 + pslot * 8;
  const u16* pA2 = pA1 + 16 * 768;
  const u16* pB1 = BT + (size_t)(nt * 256 + cidA * 16 + srow) * 768 + pslot * 8;
  const u16* pB2 = pB1 + 16 * 768;

  // fragment read offsets (u16 units): row*32 + rsel*8 within a 16KB slot
  int rsel = g ^ ((c4 >> 1) & 3);
  int aoff = wr * 4096 + c4 * 32 + rsel * 8;
  int boff = wc * 2048 + c4 * 32 + rsel * 8;

  f32x4 acc[8][4];
  f32x4 z4 = {0.f, 0.f, 0.f, 0.f};
  #pragma unroll
  for (int f = 0; f < 8; f++)
    #pragma unroll
    for (int fc = 0; fc < 4; fc++) acc[f][fc] = z4;

  // prologue: stage K-tiles 0,1,2
  #pragma unroll
  for (int kk = 0; kk < 3; kk++) {
    u16* dA = SMEM + kk * 8192;
    GLOAD16(pA1 + kk * 32, dA + cidA * 512);
    GLOAD16(pA2 + kk * 32, dA + (cidA + 1) * 512);
    u16* dB = SMEM + 32768 + kk * 8192;
    GLOAD16(pB1 + kk * 32, dB + cidA * 512);
    GLOAD16(pB2 + kk * 32, dB + (cidA + 1) * 512);
  }
  asm volatile("s_waitcnt vmcnt(8)" ::: "memory");
  __builtin_amdgcn_s_barrier();

  for (int k = 0; k < 24; ++k) {
    const u16* As = SMEM + (k & 3) * 8192;
    const u16* Bs = SMEM + 32768 + (k & 3) * 8192;
    bf16x8 bfr[4], afr[4];
    #pragma unroll
    for (int fc = 0; fc < 4; fc++) bfr[fc] = *(const bf16x8*)(Bs + boff + fc * 512);
    #pragma unroll
    for (int f = 0; f < 4; f++) afr[f] = *(const bf16x8*)(As + aoff + f * 512);
    if (k < 21) {
      u16* d = SMEM + ((k + 3) & 3) * 8192;
      GLOAD16(pA1 + (k + 3) * 32, d + cidA * 512);
      GLOAD16(pA2 + (k + 3) * 32, d + (cidA + 1) * 512);
      asm volatile("s_waitcnt vmcnt(6)" ::: "memory");
    } else if (k == 21) {
      asm volatile("s_waitcnt vmcnt(0)" ::: "memory");
    }
    __builtin_amdgcn_s_barrier();
    __builtin_amdgcn_s_setprio(1);
    #pragma unroll
    for (int f = 0; f < 4; f++)
      #pragma unroll
      for (int fc = 0; fc < 4; fc++)
        acc[f][fc] = MFMA16(afr[f], bfr[fc], acc[f][fc]);
    __builtin_amdgcn_s_setprio(0);

    #pragma unroll
    for (int f = 0; f < 4; f++) afr[f] = *(const bf16x8*)(As + aoff + (4 + f) * 512);
    if (k < 21) {
      u16* d = SMEM + 32768 + ((k + 3) & 3) * 8192;
      GLOAD16(pB1 + (k + 3) * 32, d + cidA * 512);
      GLOAD16(pB2 + (k + 3) * 32, d + (cidA + 1) * 512);
      asm volatile("s_waitcnt vmcnt(6)" ::: "memory");
    }
    __builtin_amdgcn_s_barrier();
    __builtin_amdgcn_s_setprio(1);
    #pragma unroll
    for (int f = 0; f < 4; f++)
      #pragma unroll
      for (int fc = 0; fc < 4; fc++)
        acc[4 + f][fc] = MFMA16(afr[f], bfr[fc], acc[4 + f][fc]);
    __builtin_amdgcn_s_setprio(0);
  }

  // epilogue: direct scattered stores (R2-proven: 0 conflicts, ideal WRITE_SIZE)
  int i3 = nt / 3;
  u16* dst = (i3 == 0) ? qo : (i3 == 1) ? ko : vo;
  int head = (nt - i3 * 3) * 4 + wc;
  float bsv[4];
  #pragma unroll
  for (int fc = 0; fc < 4; fc++) bsv[fc] = bias[nt * 256 + wc * 64 + fc * 16 + c4];

  int mbase = mt * 256 + wr * 128 + g * 4;
  #pragma unroll
  for (int f = 0; f < 8; f++) {
    #pragma unroll
    for (int j = 0; j < 4; j++) {
      int mm = mbase + f * 16 + j;
      int bb2 = mm / 196, ll = mm - bb2 * 196;
      size_t ro = (size_t)((head * 128 + bb2) * 196 + ll) * 64;
      #pragma unroll
      for (int fc = 0; fc < 4; fc++)
        dst[ro + fc * 16 + c4] = f2bf(acc[f][fc][j] + bsv[fc]);
    }
  }
}

// =========================================================================
// K3: 128x128 BK=32 pipelined proj GEMM. 256 thr = 4 waves (2x2).
// Same 4-slot counted-vmcnt schedule, R2 conflict-free layout. 64KB -> 2 blk/CU.
// =========================================================================
__global__ __launch_bounds__(256, 2) void k_proj256(
    const u16* __restrict__ A, const u16* __restrict__ BT, const float* __restrict__ bias,
    float* __restrict__ out)
{
  __shared__ u16 SMEM[32768];   // A slots [0,16384), B slots [16384,32768)

  int bid0 = blockIdx.x;
  int bid = (bid0 & 7) * 147 + (bid0 >> 3);   // 1176 = 8*147
  int nt = bid % 6, mt = bid / 6;

  int tid = threadIdx.x, lane = tid & 63, w = tid >> 6;
  int g = lane >> 4, c4 = lane & 15;
  int wr = w >> 1, wc = w & 1;

  int srow = lane >> 2;
  int pslot = (lane & 3) ^ ((lane >> 3) & 3);
  int cidA = w * 2;

  const u16* pA1 = A + (size_t)(mt * 128 + cidA * 16 + srow) * 768 + pslot * 8;
  const u16* pA2 = pA1 + 16 * 768;
  const u16* pB1 = BT + (size_t)(nt * 128 + cidA * 16 + srow) * 768 + pslot * 8;
  const u16* pB2 = pB1 + 16 * 768;

  int rsel = g ^ ((c4 >> 1) & 3);
  int aoff = wr * 2048 + c4 * 32 + rsel * 8;
  int boff = wc * 2048 + c4 * 32 + rsel * 8;

  f32x4 acc[4][4];
  f32x4 z4 = {0.f, 0.f, 0.f, 0.f};
  #pragma unroll
  for (int f = 0; f < 4; f++)
    #pragma unroll
    for (int fc = 0; fc < 4; fc++) acc[f][fc] = z4;

  #pragma unroll
  for (int kk = 0; kk < 3; kk++) {
    u16* dA = SMEM + kk * 4096;
    GLOAD16(pA1 + kk * 32, dA + cidA * 512);
    GLOAD16(pA2 + kk * 32, dA + (cidA + 1) * 512);
    u16* dB = SMEM + 16384 + kk * 4096;
    GLOAD16(pB1 + kk * 32, dB + cidA * 512);
    GLOAD16(pB2 + kk * 32, dB + (cidA + 1) * 512);
  }
  asm volatile("s_waitcnt vmcnt(8)" ::: "memory");
  __builtin_amdgcn_s_barrier();

  for (int k = 0; k < 24; ++k) {
    const u16* As = SMEM + (k & 3) * 4096;
    const u16* Bs = SMEM + 16384 + (k & 3) * 4096;
    bf16x8 bfr[4], afr[4];
    #pragma unroll
    for (int fc = 0; fc < 4; fc++) bfr[fc] = *(const bf16x8*)(Bs + boff + fc * 512);
    #pragma unroll
    for (int f = 0; f < 4; f++) afr[f] = *(const bf16x8*)(As + aoff + f * 512);
    if (k < 21) {
      u16* dA = SMEM + ((k + 3) & 3) * 4096;
      GLOAD16(pA1 + (k + 3) * 32, dA + cidA * 512);
      GLOAD16(pA2 + (k + 3) * 32, dA + (cidA + 1) * 512);
      u16* dB = SMEM + 16384 + ((k + 3) & 3) * 4096;
      GLOAD16(pB1 + (k + 3) * 32, dB + cidA * 512);
      GLOAD16(pB2 + (k + 3) * 32, dB + (cidA + 1) * 512);
      asm volatile("s_waitcnt vmcnt(8)" ::: "memory");
    } else if (k == 21) {
      asm volatile("s_waitcnt vmcnt(4)" ::: "memory");
    } else if (k == 22) {
      asm volatile("s_waitcnt vmcnt(0)" ::: "memory");
    }
    __builtin_amdgcn_s_barrier();
    __builtin_amdgcn_s_setprio(1);
    #pragma unroll
    for (int f = 0; f < 4; f++)
      #pragma unroll
      for (int fc = 0; fc < 4; fc++)
        acc[f][fc] = MFMA16(afr[f], bfr[fc], acc[f][fc]);
    __builtin_amdgcn_s_setprio(0);
    __builtin_amdgcn_s_barrier();
  }

  #pragma unroll
  for (int fc = 0; fc < 4; fc++) {
    int n0 = nt * 128 + wc * 64 + fc * 16 + c4;
    float bs = bias[n0];
    #pragma unroll
    for (int fr = 0; fr < 4; fr++)
      #pragma unroll
      for (int j = 0; j < 4; j++) {
        int m = mt * 128 + wr * 64 + fr * 16 + g * 4 + j;
        out[(size_t)m * 768 + n0] = acc[fr][fc][j] + bs;
      }
  }
}

// ---------------- K2: fused attention (R2 verbatim) ----------------
#define VP 232
__global__ __launch_bounds__(256, 2) void k_attn(
    const u16* __restrict__ Q, const u16* __restrict__ Kg, const u16* __restrict__ Vg,
    const u16* __restrict__ RPH, const u16* __restrict__ RPW, u16* __restrict__ Ows)
{
  __shared__ u16 K64[208 * 64];
  __shared__ u16 Krel[208 * 40];
  __shared__ u16 VT[64 * VP];
  __shared__ u16 Qrel[4][16 * 40];

  int bh = blockIdx.x;
  int hh = bh >> 7, bb = bh & 127;
  int tid = threadIdx.x, lane = tid & 63, w = tid >> 6;
  int g = lane >> 4, c4 = lane & 15;

  const u16* kbase = Kg + (size_t)bh * 12544;
  const u16* vbase = Vg + (size_t)bh * 12544;
  const u16* qbase = Q + (size_t)bh * 12544;

  // stage K64 (scaled by 1/8, slot-XOR)
  for (int ch = tid; ch < 1664; ch += 256) {
    int row = ch >> 3, s = ch & 7;
    u16 outv[8];
    if (row < 196) {
      u16x8 v = *(const u16x8*)(kbase + row * 64 + s * 8);
      #pragma unroll
      for (int e = 0; e < 8; e++)
        outv[e] = f2bf(bits2f((uint32_t)v[e] << 16) * 0.125f);
    } else {
      #pragma unroll
      for (int e = 0; e < 8; e++) outv[e] = 0;
    }
    *(int4*)(K64 + row * 64 + ((s ^ (row & 7)) * 8)) = pack8(outv);
  }
  // Krel one-hots
  if (tid < 208) {
    int k = tid;
    int kh = k / 14, kw2 = k - kh * 14;
    #pragma unroll
    for (int s = 0; s < 5; s++) {
      u16 vals[8];
      #pragma unroll
      for (int e = 0; e < 8; e++) {
        int c = s * 8 + e;
        u16 x = 0;
        if (k < 196) {
          if (c == kh) x = 0x3F80;
          else if (c == 14 + kw2) x = 0x3F80;
        } else {
          if (c == 28) x = 0x3F80;
        }
        vals[e] = x;
      }
      *(int4*)(Krel + k * 40 + s * 8) = pack8(vals);
    }
  }
  // VT zero pad cols
  for (int i = tid; i < 2048; i += 256) {
    int chn = i >> 5, c = 192 + (i & 31);
    if (c >= 196 && c < VP) VT[chn * VP + c] = 0;
  }
  // VT stage (pair-permuted cols)
  for (int ch2 = tid; ch2 < 784; ch2 += 256) {
    int kp = ch2 >> 3, cb = ch2 & 7;
    int key = kp * 2, cz = cb * 8;
    u16x8 a = *(const u16x8*)(vbase + key * 64 + cz);
    u16x8 b2 = *(const u16x8*)(vbase + (key + 1) * 64 + cz);
    int kk = key & 31;
    int colp = (key >> 5) * 32 + ((kk & 15) >> 2) * 8 + (kk & 3) + ((kk >> 4) << 2);
    #pragma unroll
    for (int j = 0; j < 8; j++) {
      uint32_t pk = (uint32_t)a[j] | ((uint32_t)b2[j] << 16);
      *(uint32_t*)(VT + (cz + j) * VP + colp) = pk;
    }
  }
  __syncthreads();

  int t1 = 16 + c4; if (t1 > 26) t1 = 26;
  bf16x8 rh00 = *(const bf16x8*)(RPH + c4 * 64 + g * 8);
  bf16x8 rh01 = *(const bf16x8*)(RPH + c4 * 64 + 32 + g * 8);
  bf16x8 rh10 = *(const bf16x8*)(RPH + t1 * 64 + g * 8);
  bf16x8 rh11 = *(const bf16x8*)(RPH + t1 * 64 + 32 + g * 8);
  bf16x8 rw00 = *(const bf16x8*)(RPW + c4 * 64 + g * 8);
  bf16x8 rw01 = *(const bf16x8*)(RPW + c4 * 64 + 32 + g * 8);
  bf16x8 rw10 = *(const bf16x8*)(RPW + t1 * 64 + g * 8);
  bf16x8 rw11 = *(const bf16x8*)(RPW + t1 * 64 + 32 + g * 8);

  f32x4 z4 = {0.f, 0.f, 0.f, 0.f};

  for (int qt = w; qt < 13; qt += 4) {
    int qi = qt * 16 + c4;
    int qrow = qi > 195 ? 195 : qi;
    bf16x8 qa0 = *(const bf16x8*)(qbase + qrow * 64 + g * 8);
    bf16x8 qa1 = *(const bf16x8*)(qbase + qrow * 64 + 32 + g * 8);

    u16* Qr = (u16*)Qrel[w];
    {
      int4 zz = {0, 0, 0, 0};
      *(int4*)(Qr + lane * 8) = zz;
      if (lane < 16) *(int4*)(Qr + 512 + lane * 8) = zz;
      if (g == 0) Qr[c4 * 40 + 28] = f2bf(-30000.f);
    }

    int qh = qi / 14;
    int qwv = qi - qh * 14;

    f32x4 e0 = MFMA16(rh00, qa0, z4); e0 = MFMA16(rh01, qa1, e0);
    f32x4 e1 = MFMA16(rh10, qa0, z4); e1 = MFMA16(rh11, qa1, e1);
    #pragma unroll
    for (int tt = 0; tt < 2; tt++) {
      f32x4 e = tt ? e1 : e0;
      #pragma unroll
      for (int j = 0; j < 4; j++) {
        int t = tt * 16 + 4 * g + j;
        int kh = qh + 13 - t;
        if ((unsigned)kh <= 13u) Qr[c4 * 40 + kh] = f2bf(e[j]);
      }
    }
    f32x4 f0 = MFMA16(rw00, qa0, z4); f0 = MFMA16(rw01, qa1, f0);
    f32x4 f1 = MFMA16(rw10, qa0, z4); f1 = MFMA16(rw11, qa1, f1);
    #pragma unroll
    for (int tt = 0; tt < 2; tt++) {
      f32x4 e = tt ? f1 : f0;
      #pragma unroll
      for (int j = 0; j < 4; j++) {
        int t = tt * 16 + 4 * g + j;
        int kw3 = qwv + 13 - t;
        if ((unsigned)kw3 <= 13u) Qr[c4 * 40 + 14 + kw3] = f2bf(e[j]);
      }
    }

    bf16x8 qrelB = *(const bf16x8*)(Qr + c4 * 40 + g * 8);

    f32x4 St[13];
    #pragma unroll
    for (int i = 0; i < 13; i++) {
      int key = i * 16 + c4;
      const u16* kr = K64 + key * 64;
      int sw = key & 7;
      bf16x8 kb0 = *(const bf16x8*)(kr + ((g ^ sw) * 8));
      bf16x8 kb1 = *(const bf16x8*)(kr + (((4 + g) ^ sw) * 8));
      f32x4 acc = MFMA16(kb0, qa0, z4);
      acc = MFMA16(kb1, qa1, acc);
      bf16x8 krl = *(const bf16x8*)(Krel + key * 40 + g * 8);
      St[i] = MFMA16(krl, qrelB, acc);
    }

    float mx = -3.0e38f;
    #pragma unroll
    for (int i = 0; i < 13; i++)
      #pragma unroll
      for (int j = 0; j < 4; j++) mx = fmaxf(mx, St[i][j]);
    mx = fmaxf(mx, __shfl_xor(mx, 16));
    mx = fmaxf(mx, __shfl_xor(mx, 32));

    float ls = 0.f;
    f32x4 O[4] = {z4, z4, z4, z4};
    #pragma unroll
    for (int p = 0; p < 7; p++) {
      float pe[8];
      #pragma unroll
      for (int j2 = 0; j2 < 4; j2++) { pe[j2] = __expf(St[2 * p][j2] - mx); ls += pe[j2]; }
      if (p < 6) {
        #pragma unroll
        for (int j2 = 0; j2 < 4; j2++) { pe[4 + j2] = __expf(St[2 * p + 1][j2] - mx); ls += pe[4 + j2]; }
      } else {
        #pragma unroll
        for (int j2 = 0; j2 < 4; j2++) pe[4 + j2] = 0.f;
      }
      union { uint32_t u[4]; bf16x8 v; } pb;
      pb.u[0] = cvtpk(pe[0], pe[1]);
      pb.u[1] = cvtpk(pe[2], pe[3]);
      pb.u[2] = cvtpk(pe[4], pe[5]);
      pb.u[3] = cvtpk(pe[6], pe[7]);
      #pragma unroll
      for (int ct = 0; ct < 4; ct++) {
        bf16x8 va = *(const bf16x8*)(VT + (ct * 16 + c4) * VP + p * 32 + g * 8);
        O[ct] = MFMA16(va, pb.v, O[ct]);
      }
    }
    ls += __shfl_xor(ls, 16);
    ls += __shfl_xor(ls, 32);

    if (qi < 196) {
      float inv = 1.f / ls;
      size_t obase = (size_t)(bb * 196 + qi) * 768 + hh * 64;
      #pragma unroll
      for (int ct = 0; ct < 4; ct++) {
        uint32_t o0 = cvtpk(O[ct][0] * inv, O[ct][1] * inv);
        uint32_t o1 = cvtpk(O[ct][2] * inv, O[ct][3] * inv);
        uint2 ov = {o0, o1};
        *(uint2*)(Ows + obase + ct * 16 + g * 4) = ov;
      }
    }
  }
}

// ---------------- host launch ----------------
extern "C" void kernel_launch(void* const* d_in, const int* in_sizes, int n_in,
                              void* d_out, int out_size, void* d_ws, size_t ws_size,
                              hipStream_t stream) {
  (void)in_sizes; (void)n_in; (void)out_size; (void)ws_size;
  const float* x      = (const float*)d_in[0];
  const float* qkv_w  = (const float*)d_in[1];
  const float* qkv_b  = (const float*)d_in[2];
  const float* proj_w = (const float*)d_in[3];
  const float* proj_b = (const float*)d_in[4];
  const float* rph    = (const float*)d_in[5];
  const float* rpw    = (const float*)d_in[6];
  float* out = (float*)d_out;
  char* ws = (char*)d_ws;

  u16* xb   = (u16*)(ws);                 // 25088x768 bf16
  u16* wT   = (u16*)(ws + 38535168);      // 2304x768 bf16
  u16* pT   = (u16*)(ws + 42074112);      // 768x768 bf16
  u16* rphb = (u16*)(ws + 43253760);      // 27x64 bf16
  u16* rpwb = (u16*)(ws + 43257856);      // 27x64 bf16
  u16* qws  = (u16*)(ws + 43261952);      // 1536x196x64 bf16
  u16* kws  = (u16*)(ws + 81797120);
  u16* vws  = (u16*)(ws + 120332288);
  u16* Ows  = xb;                         // xb dead after K1

  k_cvt<<<2048, 256, 0, stream>>>(x, xb, 4816896);
  k_cvt<<<2, 256, 0, stream>>>(rph, rphb, 432);
  k_cvt<<<2, 256, 0, stream>>>(rpw, rpwb, 432);
  k_transpose<<<dim3(72, 24), 256, 0, stream>>>(qkv_w, wT, 768, 2304);
  k_transpose<<<dim3(24, 24), 256, 0, stream>>>(proj_w, pT, 768, 768);
  k_qkv256<<<882, 512, 0, stream>>>(xb, wT, qkv_b, qws, kws, vws);
  k_attn<<<1536, 256, 0, stream>>>(qws, kws, vws, rphb, rpwb, Ows);
  k_proj256<<<1176, 256, 0, stream>>>(Ows, pT, proj_b, out);
}